// Round 1
// baseline (159.837 us; speedup 1.0000x reference)
//
#include <hip/hip_runtime.h>

#define GC 32768
#define GN (2*GC)
#define GE (3*GC-2)

// msg = W2 @ relu(W1 @ [d; s; e] + B1) + B2
template<int F, int H, int O>
__device__ __forceinline__ void edge_msg(
    const float* d, const float* s, const float* ee,
    const float* __restrict__ W1, const float* __restrict__ B1,
    const float* __restrict__ W2, const float* __restrict__ B2,
    float* out)
{
    float z[H];
#pragma unroll
    for (int h = 0; h < H; ++h) {
        float acc = B1[h];
        const float* w = W1 + h * (2 * F + 4);
#pragma unroll
        for (int f = 0; f < F; ++f) acc = fmaf(d[f], w[f], acc);
#pragma unroll
        for (int f = 0; f < F; ++f) acc = fmaf(s[f], w[F + f], acc);
#pragma unroll
        for (int k = 0; k < 4; ++k) acc = fmaf(ee[k], w[2 * F + k], acc);
        z[h] = fmaxf(acc, 0.0f);
    }
#pragma unroll
    for (int o = 0; o < O; ++o) {
        float acc = B2[o];
#pragma unroll
        for (int h = 0; h < H; ++h) acc = fmaf(z[h], W2[o * H + h], acc);
        out[o] = acc;
    }
}

// One edge-conv layer for column j (both rows).
// c0/c1: this column's features (row0/row1); p0/p1: column j-1 (from shfl).
template<int F, int H, int O>
__device__ __forceinline__ void layer_step(
    const float* c0, const float* c1, const float* p0, const float* p1,
    const float* eh1, const float* eh2, const float* ev, bool jpos,
    const float* __restrict__ W1, const float* __restrict__ B1,
    const float* __restrict__ W2, const float* __restrict__ B2,
    float* o0, float* o1)
{
    float oh0[O], oh1[O], ov[O];
    edge_msg<F, H, O>(c0, p0, eh1, W1, B1, W2, B2, oh0);  // row0: dst=j, src=j-1
    edge_msg<F, H, O>(c1, p1, eh2, W1, B1, W2, B2, oh1);  // row1 horizontal
    edge_msg<F, H, O>(c1, c0, ev,  W1, B1, W2, B2, ov);   // vertical: dst=row1, src=row0
#pragma unroll
    for (int o = 0; o < O; ++o) {
        o0[o] = jpos ? oh0[o] : 0.0f;               // node 0 row0: no in-edges -> 0
        o1[o] = jpos ? fmaxf(ov[o], oh1[o]) : ov[o]; // segment_max over <=2 edges
    }
}

__global__ __launch_bounds__(256) void gnn_fused(
    const float* __restrict__ x, const float* __restrict__ e,
    const float* __restrict__ w1a, const float* __restrict__ b1a,
    const float* __restrict__ w1b, const float* __restrict__ b1b,
    const float* __restrict__ w2a, const float* __restrict__ b2a,
    const float* __restrict__ w2b, const float* __restrict__ b2b,
    const float* __restrict__ w3a, const float* __restrict__ b3a,
    const float* __restrict__ w3b, const float* __restrict__ b3b,
    const float* __restrict__ wmu, const float* __restrict__ bmu,
    float* __restrict__ out)
{
    constexpr int WPB = (GC + 61) / 62;  // 529 waves per batch row
    const int gtid = blockIdx.x * blockDim.x + threadIdx.x;
    const int wave = gtid >> 6;
    const int lane = gtid & 63;
    const int b    = wave / WPB;
    const int tile = wave - b * WPB;
    const int j    = tile * 62 + lane - 2;   // lanes 0,1 = halo

    const int jc = j < 0 ? 0 : (j >= GC ? GC - 1 : j);
    const int jm = jc > 0 ? jc - 1 : 0;
    const bool jpos = (j >= 1);

    const size_t xb = (size_t)b * GN * 2;
    const size_t eb = (size_t)b * GE * 4;

    const float2 xc0 = *(const float2*)(x + xb + (size_t)jc * 2);
    const float2 xp0 = *(const float2*)(x + xb + (size_t)jm * 2);
    const float2 xc1 = *(const float2*)(x + xb + ((size_t)GC + jc) * 2);
    const float2 xp1 = *(const float2*)(x + xb + ((size_t)GC + jm) * 2);
    const float4 v_eh1 = *(const float4*)(e + eb + (size_t)jm * 4);
    const float4 v_eh2 = *(const float4*)(e + eb + ((size_t)(GC - 1) + jm) * 4);
    const float4 v_ev  = *(const float4*)(e + eb + ((size_t)(2 * (GC - 1)) + jc) * 4);

    float c0[2] = {xc0.x, xc0.y}, c1[2] = {xc1.x, xc1.y};
    float p0[2] = {xp0.x, xp0.y}, p1[2] = {xp1.x, xp1.y};
    float eh1[4] = {v_eh1.x, v_eh1.y, v_eh1.z, v_eh1.w};
    float eh2[4] = {v_eh2.x, v_eh2.y, v_eh2.z, v_eh2.w};
    float ev[4]  = {v_ev.x,  v_ev.y,  v_ev.z,  v_ev.w};

    // ---- layer 1: F=2 -> H=4 -> O=4
    float h10[4], h11[4];
    layer_step<2, 4, 4>(c0, c1, p0, p1, eh1, eh2, ev, jpos,
                        w1a, b1a, w1b, b1b, h10, h11);

    float q10[4], q11[4];
#pragma unroll
    for (int i = 0; i < 4; ++i) {
        q10[i] = __shfl_up(h10[i], 1);
        q11[i] = __shfl_up(h11[i], 1);
    }

    // ---- layer 2: F=4 -> H=8 -> O=8
    float h20[8], h21[8];
    layer_step<4, 8, 8>(h10, h11, q10, q11, eh1, eh2, ev, jpos,
                        w2a, b2a, w2b, b2b, h20, h21);

    float q20[8], q21[8];
#pragma unroll
    for (int i = 0; i < 8; ++i) {
        q20[i] = __shfl_up(h20[i], 1);
        q21[i] = __shfl_up(h21[i], 1);
    }

    // ---- layer 3: F=8 -> H=16 -> O=16
    float h30[16], h31[16];
    layer_step<8, 16, 16>(h20, h21, q20, q21, eh1, eh2, ev, jpos,
                          w3a, b3a, w3b, b3b, h30, h31);

    // ---- mu: concat(row0[16], row1[16]) . wmu + bmu
    float acc = bmu[0];
#pragma unroll
    for (int f = 0; f < 16; ++f) acc = fmaf(h30[f], wmu[f], acc);
#pragma unroll
    for (int f = 0; f < 16; ++f) acc = fmaf(h31[f], wmu[16 + f], acc);

    if (lane >= 2 && j < GC)
        out[(size_t)b * GC + j] = acc;
}

extern "C" void kernel_launch(void* const* d_in, const int* in_sizes, int n_in,
                              void* d_out, int out_size, void* d_ws, size_t ws_size,
                              hipStream_t stream) {
    const float* x   = (const float*)d_in[0];
    const float* e   = (const float*)d_in[1];
    // d_in[2]=src, d_in[3]=dst unused (structure is known statically)
    const float* w1a = (const float*)d_in[4];
    const float* b1a = (const float*)d_in[5];
    const float* w1b = (const float*)d_in[6];
    const float* b1b = (const float*)d_in[7];
    const float* w2a = (const float*)d_in[8];
    const float* b2a = (const float*)d_in[9];
    const float* w2b = (const float*)d_in[10];
    const float* b2b = (const float*)d_in[11];
    const float* w3a = (const float*)d_in[12];
    const float* b3a = (const float*)d_in[13];
    const float* w3b = (const float*)d_in[14];
    const float* b3b = (const float*)d_in[15];
    const float* wmu = (const float*)d_in[16];
    const float* bmu = (const float*)d_in[17];
    float* out = (float*)d_out;

    constexpr int WPB = (GC + 61) / 62;          // 529
    const int total_waves = 64 * WPB;            // 33856
    const int blocks = (total_waves * 64) / 256; // 8464

    hipLaunchKernelGGL(gnn_fused, dim3(blocks), dim3(256), 0, stream,
                       x, e, w1a, b1a, w1b, b1b, w2a, b2a, w2b, b2b,
                       w3a, b3a, w3b, b3b, wmu, bmu, out);
}